// Round 13
// baseline (369.029 us; speedup 1.0000x reference)
//
#include <hip/hip_runtime.h>
#include <math.h>

#define NB 512
#define NL 336
#define NC 321
#define NS 28
#define NW 12
#define NH 25
#define NP 8
#define NG 100
#define NT (NS + NP - 1)  // 35 cell steps
#define BSL 16            // batches per wave (1 MFMA column-tile)
#define WPB 4             // independent waves per 256-thread block
#define LOG2E 1.44269504088896340736f
#define N2LOG2E -2.88539008177792681472f

typedef __attribute__((ext_vector_type(8))) _Float16 f16x8;
typedef __attribute__((ext_vector_type(4))) float f32x4;

union F8 { f16x8 v; _Float16 h[8]; };

// 1/x for positive normal x: bit-trick seed + 3 Newton (rel err ~1e-7).
// Runs on the main VALU pipe — keeps the trans pipe free for the 40 exps.
__device__ __forceinline__ float frcp3(float x) {
    union { float f; unsigned u; } v; v.f = x;
    v.u = 0x7EF311C3u - v.u;
    float r = v.f;
    r = r * fmaf(-x, r, 2.0f);
    r = r * fmaf(-x, r, 2.0f);
    r = r * fmaf(-x, r, 2.0f);
    return r;
}

// q==3 lane carries the extra K-slots: k25=xt, k26=1.0 (A=bias row), k27..31=0
__device__ __forceinline__ void set_q3f(F8& b, bool q3, float xt) {
    b.h[1] = q3 ? (_Float16)xt : b.h[1];
    b.h[2] = q3 ? (_Float16)1.0f : b.h[2];
    b.h[3] = q3 ? (_Float16)0.0f : b.h[3];
    b.h[4] = q3 ? (_Float16)0.0f : b.h[4];
    b.h[5] = q3 ? (_Float16)0.0f : b.h[5];
    b.h[6] = q3 ? (_Float16)0.0f : b.h[6];
    b.h[7] = q3 ? (_Float16)0.0f : b.h[7];
}

// ---------------- Stage 1: mean + segment embedding (transposed out) --------
// Fully unrolled: acc[] statically indexed (no scratch), 4 partial sums break
// the serial reduce chain, ~48 loads in flight for latency cover.
extern "C" __global__ __launch_bounds__(384)
void k_seg(const float* __restrict__ x, const float* __restrict__ seg,
           float* __restrict__ seg_inT, float* __restrict__ meanw) {
    const int b = blockIdx.x;
    const int c = threadIdx.x;
    if (c >= NC) return;
    float sw[NW];
#pragma unroll
    for (int w = 0; w < NW; ++w) sw[w] = seg[c * NW + w];
    float acc[NS];
    float sum0 = 0.0f, sum1 = 0.0f, sum2 = 0.0f, sum3 = 0.0f;
    const float* xb = x + (size_t)b * NL * NC + c;
#pragma unroll
    for (int s = 0; s < NS; ++s) {
        float a = 0.0f;
        float t0 = 0.0f, t1 = 0.0f, t2 = 0.0f, t3 = 0.0f;
#pragma unroll
        for (int w = 0; w < NW; w += 4) {
            const float v0 = xb[(s * NW + w) * NC];
            const float v1 = xb[(s * NW + w + 1) * NC];
            const float v2 = xb[(s * NW + w + 2) * NC];
            const float v3 = xb[(s * NW + w + 3) * NC];
            t0 += v0; t1 += v1; t2 += v2; t3 += v3;
            a = fmaf(v0, sw[w], a);
            a = fmaf(v1, sw[w + 1], a);
            a = fmaf(v2, sw[w + 2], a);
            a = fmaf(v3, sw[w + 3], a);
        }
        sum0 += t0; sum1 += t1; sum2 += t2; sum3 += t3;
        acc[s] = a;
    }
    const float mean = ((sum0 + sum1) + (sum2 + sum3)) * (1.0f / (float)NL);
    float ssum = 0.0f;
#pragma unroll
    for (int w = 0; w < NW; ++w) ssum += sw[w];
    meanw[b * NC + c] = mean;
#pragma unroll
    for (int s = 0; s < NS; ++s)
        seg_inT[((size_t)s * NC + c) * NB + b] = acc[s] - mean * ssum;
}

// ---------------- Stage 2: f16-MFMA LSTM, zero-LDS recurrence ---------------
// 4 independent waves per 256-thread block (no barriers, no LDS); each wave
// owns (channel, 16-batch tile). Gate rows permuted j=q*8+mg: lane (bb,q)
// owns h[8q..8q+7] of batch bb == exactly its next-step B-fragment slots.
// f16 weights/h; gates emerge pre-scaled into exp2 domain -> single v_exp_f32
// each; reciprocals on the VALU pipe (frcp3) since trans throughput is the
// binding resource (~16 cyc/wave64 inferred R9-R12).
extern "C" __global__ __launch_bounds__(256, 4)
void k_lstm(const float* __restrict__ seg_inT, const float* __restrict__ W_ih,
            const float* __restrict__ W_hh, const float* __restrict__ b_ih,
            const float* __restrict__ b_hh, const float* __restrict__ Wp,
            const float* __restrict__ bp, float* __restrict__ preds) {
    const int c = blockIdx.x;
    const int wv = threadIdx.x >> 6;
    const int lane = threadIdx.x & 63;
    const int b0 = (blockIdx.y * WPB + wv) * BSL;
    const int bb = lane & 15;         // column (batch) / A-row
    const int q  = lane >> 4;         // k-chunk / C row-quad
    const bool q3 = (q == 3);

    // ---- hoisted A-fragments from global (one-time, L2/L3-resident) ----
    const int qq = bb >> 2, rr = bb & 3;
    const float srow = (rr == 2) ? 2.88539008177792681472f : LOG2E;
    const float* __restrict__ whh = W_hh + (size_t)c * NG * NH;
    const float* __restrict__ wxp = W_ih + (size_t)c * NG;
    const float* __restrict__ bip = b_ih + (size_t)c * NG;
    const float* __restrict__ bhp = b_hh + (size_t)c * NG;
    F8 afr[8];
#pragma unroll 1
    for (int mg = 0; mg < 8; ++mg) {
        const int jj = qq * 8 + mg;
        const int grow = rr * NH + jj;
        F8 f0;
#pragma unroll
        for (int e = 0; e < 8; ++e) {
            const int k = q * 8 + e;
            float v0 = 0.0f;
            if (jj < NH) {
                if (k < NH)         v0 = whh[grow * NH + k] * srow;
                else if (k == 25)   v0 = wxp[grow] * srow;
                else if (k == 26)   v0 = (bip[grow] + bhp[grow]) * srow;
            }
            f0.h[e] = (_Float16)v0;
        }
        afr[mg] = f0;
    }

    float wpl[8];
#pragma unroll
    for (int mg = 0; mg < 8; ++mg) {
        const int j = q * 8 + mg;
        wpl[mg] = (j < NH) ? Wp[(size_t)c * NH + j] : 0.0f;
    }
    const float bpc = bp[c];

    // ---- initial B-fragment: h = 0, xt = seg_in[s=0] ----
    F8 ph;
    {
        const float x0 = seg_inT[(size_t)c * NB + b0 + bb];
#pragma unroll
        for (int e = 0; e < 8; ++e) ph.h[e] = (_Float16)0.0f;
        set_q3f(ph, q3, x0);
    }

    float cst[8];
#pragma unroll
    for (int mg = 0; mg < 8; ++mg) cst[mg] = 0.0f;

    // ---- recurrence: pure register dataflow, phase-structured ----
#pragma unroll 1
    for (int t = 0; t < NT; ++t) {
        const bool enc_next = (t + 1 < NS);
        const bool do_proj = (t >= NS - 1);
        const bool have_next = (t + 1 < NT);

        // prefetch next encoder input early (L2/L3-resident)
        float xn = 0.0f;
        if (enc_next)
            xn = seg_inT[((size_t)(t + 1) * NC + c) * NB + b0 + bb];

        // phase 1: all 8 MFMAs (independent, single per gate-tile)
        f32x4 av[8];
#pragma unroll
        for (int mg = 0; mg < 8; ++mg) {
            f32x4 z = {0.0f, 0.0f, 0.0f, 0.0f};
            av[mg] = __builtin_amdgcn_mfma_f32_16x16x32_f16(afr[mg].v, ph.v, z, 0, 0, 0);
        }

        // phase 2: all 32 gate exps (single v_exp_f32 each; exp2 domain)
        float ei[8], ef[8], eg[8], eo[8];
#pragma unroll
        for (int mg = 0; mg < 8; ++mg) {
            ei[mg] = __builtin_amdgcn_exp2f(-av[mg][0]);
            ef[mg] = __builtin_amdgcn_exp2f(-av[mg][1]);
            eg[mg] = __builtin_amdgcn_exp2f(-av[mg][2]);
            eo[mg] = __builtin_amdgcn_exp2f(-av[mg][3]);
        }

        // phase 3: per-unit tails (independent across mg; rcp on VALU pipe)
        float hnv[8];
        float pp = 0.0f;
#pragma unroll
        for (int mg = 0; mg < 8; ++mg) {
            const float p1f = 1.0f + ef[mg];
            const float pig = (1.0f + ei[mg]) * (1.0f + eg[mg]);
            const float num = fmaf(cst[mg], pig, (1.0f - eg[mg]) * p1f);
            const float cn  = num * frcp3(p1f * pig);
            const float et  = __builtin_amdgcn_exp2f(cn * N2LOG2E);
            const float hn  = (1.0f - et) * frcp3((1.0f + eo[mg]) * (1.0f + et));
            cst[mg] = cn;
            hnv[mg] = hn;
            if (do_proj) pp = fmaf(hn, wpl[mg], pp);
        }

        float ov = 0.0f;
        if (do_proj) {
            pp += __shfl_xor(pp, 16);
            pp += __shfl_xor(pp, 32);
            ov = pp + bpc;
            if (q == 0)
                preds[((size_t)c * NP + (t - (NS - 1))) * NB + b0 + bb] = ov;
        }

        if (have_next) {
            // repack h into next step's B-fragment: 8 f32->f16 converts
#pragma unroll
            for (int e = 0; e < 8; ++e) ph.h[e] = (_Float16)hnv[e];
            set_q3f(ph, q3, enc_next ? xn : ov);
        }
    }
}

// ---------------- Stage 3: expand predictions to output ---------------------
// Block (b,p) x threads c: preds/mean read once per 12 coalesced row-writes.
extern "C" __global__ __launch_bounds__(384)
void k_out(const float* __restrict__ preds, const float* __restrict__ seg,
           const float* __restrict__ meanw, float* __restrict__ out) {
    const int b = blockIdx.x;
    const int p = blockIdx.y;
    const int c = threadIdx.x;
    if (c >= NC) return;
    const float pv = preds[((size_t)c * NP + p) * NB + b];
    const float mean = meanw[b * NC + c];
    float* ob = out + ((size_t)b * (NP * NW) + p * NW) * NC + c;
#pragma unroll
    for (int w = 0; w < NW; ++w)
        ob[w * NC] = fmaf(pv, seg[c * NW + w], mean);
}

extern "C" void kernel_launch(void* const* d_in, const int* in_sizes, int n_in,
                              void* d_out, int out_size, void* d_ws, size_t ws_size,
                              hipStream_t stream) {
    const float* x    = (const float*)d_in[0];
    const float* seg  = (const float*)d_in[1];
    const float* W_ih = (const float*)d_in[2];
    const float* W_hh = (const float*)d_in[3];
    const float* b_ih = (const float*)d_in[4];
    const float* b_hh = (const float*)d_in[5];
    const float* Wp   = (const float*)d_in[6];
    const float* bp   = (const float*)d_in[7];
    float* out = (float*)d_out;

    float* seg_inT = (float*)d_ws;                     // 28*321*512
    float* meanw   = seg_inT + (size_t)NS * NC * NB;   // 512*321
    float* preds   = meanw + (size_t)NB * NC;          // 321*8*512

    k_seg<<<NB, 384, 0, stream>>>(x, seg, seg_inT, meanw);
    k_lstm<<<dim3(NC, NB / (BSL * WPB)), 256, 0, stream>>>(
        seg_inT, W_ih, W_hh, b_ih, b_hh, Wp, bp, preds);
    k_out<<<dim3(NB, NP), 384, 0, stream>>>(preds, seg, meanw, out);
}

// Round 14
// 337.483 us; speedup vs baseline: 1.0935x; 1.0935x over previous
//
#include <hip/hip_runtime.h>
#include <math.h>

#define NB 512
#define NL 336
#define NC 321
#define NS 28
#define NW 12
#define NH 25
#define NP 8
#define NG 100
#define NT (NS + NP - 1)  // 35 cell steps
#define BSL 16            // batches per wave (1 MFMA column-tile)
#define WPB 4             // independent waves per 256-thread block
#define NCHK 4            // L-chunks for stage 1 (7 segments each)
#define LOG2E 1.44269504088896340736f
#define N2LOG2E -2.88539008177792681472f

typedef __attribute__((ext_vector_type(8))) _Float16 f16x8;
typedef __attribute__((ext_vector_type(4))) float f32x4;

union F8 { f16x8 v; _Float16 h[8]; };

// q==3 lane carries the extra K-slots: k25=xt, k26=1.0 (A=bias row), k27..31=0
__device__ __forceinline__ void set_q3f(F8& b, bool q3, float xt) {
    b.h[1] = q3 ? (_Float16)xt : b.h[1];
    b.h[2] = q3 ? (_Float16)1.0f : b.h[2];
    b.h[3] = q3 ? (_Float16)0.0f : b.h[3];
    b.h[4] = q3 ? (_Float16)0.0f : b.h[4];
    b.h[5] = q3 ? (_Float16)0.0f : b.h[5];
    b.h[6] = q3 ? (_Float16)0.0f : b.h[6];
    b.h[7] = q3 ? (_Float16)0.0f : b.h[7];
}

// ---------------- Stage 1a: raw segment dots + partial sums -----------------
// Block (b, chunk): 7 segments (84 L-rows). Reads coalesced over c. Writes
// raw dots (mean correction deferred to k_lstm) + per-chunk partial sum.
extern "C" __global__ __launch_bounds__(384)
void k_seg_part(const float* __restrict__ x, const float* __restrict__ seg,
                float* __restrict__ seg_raw, float* __restrict__ psum) {
    const int b = blockIdx.x;
    const int ch = blockIdx.y;
    const int c = threadIdx.x;
    if (c >= NC) return;
    float sw[NW];
#pragma unroll
    for (int w = 0; w < NW; ++w) sw[w] = seg[c * NW + w];
    float acc[7];
    float s0 = 0.0f, s1 = 0.0f, s2 = 0.0f, s3 = 0.0f;
    const float* xb = x + ((size_t)b * NL + ch * 84) * NC + c;
#pragma unroll
    for (int i = 0; i < 7; ++i) {
        float a = 0.0f;
        float t0 = 0.0f, t1 = 0.0f, t2 = 0.0f, t3 = 0.0f;
#pragma unroll
        for (int w = 0; w < NW; w += 4) {
            const float v0 = xb[(i * NW + w) * NC];
            const float v1 = xb[(i * NW + w + 1) * NC];
            const float v2 = xb[(i * NW + w + 2) * NC];
            const float v3 = xb[(i * NW + w + 3) * NC];
            t0 += v0; t1 += v1; t2 += v2; t3 += v3;
            a = fmaf(v0, sw[w], a);
            a = fmaf(v1, sw[w + 1], a);
            a = fmaf(v2, sw[w + 2], a);
            a = fmaf(v3, sw[w + 3], a);
        }
        s0 += t0; s1 += t1; s2 += t2; s3 += t3;
        acc[i] = a;
    }
    psum[((size_t)ch * NB + b) * NC + c] = (s0 + s1) + (s2 + s3);
#pragma unroll
    for (int i = 0; i < 7; ++i) {
        const int s = ch * 7 + i;
        seg_raw[((size_t)s * NC + c) * NB + b] = acc[i];
    }
}

// ---------------- Stage 1b: reduce partial sums to means --------------------
extern "C" __global__ __launch_bounds__(384)
void k_mean(const float* __restrict__ psum, float* __restrict__ meanw,
            float* __restrict__ meanT) {
    const int b = blockIdx.x;
    const int c = threadIdx.x;
    if (c >= NC) return;
    float s = 0.0f;
#pragma unroll
    for (int ch = 0; ch < NCHK; ++ch)
        s += psum[((size_t)ch * NB + b) * NC + c];
    const float mean = s * (1.0f / (float)NL);
    meanw[b * NC + c] = mean;
    meanT[(size_t)c * NB + b] = mean;
}

// ---------------- Stage 2: f16-MFMA LSTM, zero-LDS recurrence ---------------
// (exact R12 structure — hw exp2/rcp on trans pipe; R13 showed VALU-Newton
// rcp costs ~1:1 in issue and regresses). Mean correction folded into the
// xt load: xt = raw - mean*ssum (1 fma).
extern "C" __global__ __launch_bounds__(256, 4)
void k_lstm(const float* __restrict__ seg_raw, const float* __restrict__ W_ih,
            const float* __restrict__ W_hh, const float* __restrict__ b_ih,
            const float* __restrict__ b_hh, const float* __restrict__ Wp,
            const float* __restrict__ bp, const float* __restrict__ seg,
            const float* __restrict__ meanT, float* __restrict__ preds) {
    const int c = blockIdx.x;
    const int wv = threadIdx.x >> 6;
    const int lane = threadIdx.x & 63;
    const int b0 = (blockIdx.y * WPB + wv) * BSL;
    const int bb = lane & 15;         // column (batch) / A-row
    const int q  = lane >> 4;         // k-chunk / C row-quad
    const bool q3 = (q == 3);

    // per-wave constants: ssum (wave-uniform s_loads) and this lane's mean
    float ssc = 0.0f;
#pragma unroll
    for (int w = 0; w < NW; ++w) ssc += seg[c * NW + w];
    const float mml = meanT[(size_t)c * NB + b0 + bb];
    const float mcorr = mml * ssc;

    // ---- hoisted A-fragments from global (one-time, L2/L3-resident) ----
    const int qq = bb >> 2, rr = bb & 3;
    const float srow = (rr == 2) ? 2.88539008177792681472f : LOG2E;
    const float* __restrict__ whh = W_hh + (size_t)c * NG * NH;
    const float* __restrict__ wxp = W_ih + (size_t)c * NG;
    const float* __restrict__ bip = b_ih + (size_t)c * NG;
    const float* __restrict__ bhp = b_hh + (size_t)c * NG;
    F8 afr[8];
#pragma unroll 1
    for (int mg = 0; mg < 8; ++mg) {
        const int jj = qq * 8 + mg;
        const int grow = rr * NH + jj;
        F8 f0;
#pragma unroll
        for (int e = 0; e < 8; ++e) {
            const int k = q * 8 + e;
            float v0 = 0.0f;
            if (jj < NH) {
                if (k < NH)         v0 = whh[grow * NH + k] * srow;
                else if (k == 25)   v0 = wxp[grow] * srow;
                else if (k == 26)   v0 = (bip[grow] + bhp[grow]) * srow;
            }
            f0.h[e] = (_Float16)v0;
        }
        afr[mg] = f0;
    }

    float wpl[8];
#pragma unroll
    for (int mg = 0; mg < 8; ++mg) {
        const int j = q * 8 + mg;
        wpl[mg] = (j < NH) ? Wp[(size_t)c * NH + j] : 0.0f;
    }
    const float bpc = bp[c];

    // ---- initial B-fragment: h = 0, xt = seg_in[s=0] ----
    F8 ph;
    {
        const float x0 = seg_raw[(size_t)c * NB + b0 + bb] - mcorr;
#pragma unroll
        for (int e = 0; e < 8; ++e) ph.h[e] = (_Float16)0.0f;
        set_q3f(ph, q3, x0);
    }

    float cst[8];
#pragma unroll
    for (int mg = 0; mg < 8; ++mg) cst[mg] = 0.0f;

    // ---- recurrence: pure register dataflow, phase-structured ----
#pragma unroll 1
    for (int t = 0; t < NT; ++t) {
        const bool enc_next = (t + 1 < NS);
        const bool do_proj = (t >= NS - 1);
        const bool have_next = (t + 1 < NT);

        // prefetch next encoder input early (L2/L3-resident), mean-corrected
        float xn = 0.0f;
        if (enc_next)
            xn = seg_raw[((size_t)(t + 1) * NC + c) * NB + b0 + bb] - mcorr;

        // phase 1: all 8 MFMAs (independent, single per gate-tile)
        f32x4 av[8];
#pragma unroll
        for (int mg = 0; mg < 8; ++mg) {
            f32x4 z = {0.0f, 0.0f, 0.0f, 0.0f};
            av[mg] = __builtin_amdgcn_mfma_f32_16x16x32_f16(afr[mg].v, ph.v, z, 0, 0, 0);
        }

        // phase 2: all 32 gate exps (single v_exp_f32 each; exp2 domain)
        float ei[8], ef[8], eg[8], eo[8];
#pragma unroll
        for (int mg = 0; mg < 8; ++mg) {
            ei[mg] = __builtin_amdgcn_exp2f(-av[mg][0]);
            ef[mg] = __builtin_amdgcn_exp2f(-av[mg][1]);
            eg[mg] = __builtin_amdgcn_exp2f(-av[mg][2]);
            eo[mg] = __builtin_amdgcn_exp2f(-av[mg][3]);
        }

        // phase 3: per-unit tails (independent across mg; hw rcp)
        float hnv[8];
        float pp = 0.0f;
#pragma unroll
        for (int mg = 0; mg < 8; ++mg) {
            const float p1f = 1.0f + ef[mg];
            const float pig = (1.0f + ei[mg]) * (1.0f + eg[mg]);
            const float num = fmaf(cst[mg], pig, (1.0f - eg[mg]) * p1f);
            const float cn  = num * __builtin_amdgcn_rcpf(p1f * pig);
            const float et  = __builtin_amdgcn_exp2f(cn * N2LOG2E);
            const float hn  = (1.0f - et) *
                              __builtin_amdgcn_rcpf((1.0f + eo[mg]) * (1.0f + et));
            cst[mg] = cn;
            hnv[mg] = hn;
            if (do_proj) pp = fmaf(hn, wpl[mg], pp);
        }

        float ov = 0.0f;
        if (do_proj) {
            pp += __shfl_xor(pp, 16);
            pp += __shfl_xor(pp, 32);
            ov = pp + bpc;
            if (q == 0)
                preds[((size_t)c * NP + (t - (NS - 1))) * NB + b0 + bb] = ov;
        }

        if (have_next) {
            // repack h into next step's B-fragment: 8 f32->f16 converts
#pragma unroll
            for (int e = 0; e < 8; ++e) ph.h[e] = (_Float16)hnv[e];
            set_q3f(ph, q3, enc_next ? xn : ov);
        }
    }
}

// ---------------- Stage 3: expand predictions to output ---------------------
// Block (b,p) x threads c: preds/mean read once per 12 coalesced row-writes.
extern "C" __global__ __launch_bounds__(384)
void k_out(const float* __restrict__ preds, const float* __restrict__ seg,
           const float* __restrict__ meanw, float* __restrict__ out) {
    const int b = blockIdx.x;
    const int p = blockIdx.y;
    const int c = threadIdx.x;
    if (c >= NC) return;
    const float pv = preds[((size_t)c * NP + p) * NB + b];
    const float mean = meanw[b * NC + c];
    float* ob = out + ((size_t)b * (NP * NW) + p * NW) * NC + c;
#pragma unroll
    for (int w = 0; w < NW; ++w)
        ob[w * NC] = fmaf(pv, seg[c * NW + w], mean);
}

extern "C" void kernel_launch(void* const* d_in, const int* in_sizes, int n_in,
                              void* d_out, int out_size, void* d_ws, size_t ws_size,
                              hipStream_t stream) {
    const float* x    = (const float*)d_in[0];
    const float* seg  = (const float*)d_in[1];
    const float* W_ih = (const float*)d_in[2];
    const float* W_hh = (const float*)d_in[3];
    const float* b_ih = (const float*)d_in[4];
    const float* b_hh = (const float*)d_in[5];
    const float* Wp   = (const float*)d_in[6];
    const float* bp   = (const float*)d_in[7];
    float* out = (float*)d_out;

    float* seg_raw = (float*)d_ws;                       // 28*321*512
    float* psum    = seg_raw + (size_t)NS * NC * NB;     // 4*512*321
    float* meanw   = psum + (size_t)NCHK * NB * NC;      // 512*321
    float* meanT   = meanw + (size_t)NB * NC;            // 321*512
    float* preds   = meanT + (size_t)NC * NB;            // 321*8*512

    k_seg_part<<<dim3(NB, NCHK), 384, 0, stream>>>(x, seg, seg_raw, psum);
    k_mean<<<NB, 384, 0, stream>>>(psum, meanw, meanT);
    k_lstm<<<dim3(NC, NB / (BSL * WPB)), 256, 0, stream>>>(
        seg_raw, W_ih, W_hh, b_ih, b_hh, Wp, bp, seg, meanT, preds);
    k_out<<<dim3(NB, NP), 384, 0, stream>>>(preds, seg, meanw, out);
}